// Round 11
// baseline (513.244 us; speedup 1.0000x reference)
//
#include <hip/hip_runtime.h>
#include <math.h>

#define B_   8
#define N_   3136
#define C_   256
#define NH_  8
#define HD_  32
#define LL_  9
#define PL_  49
#define HF_  682
#define HH   56
#define WW   56
#define MROWS (B_*N_)   // 25088
#define HGLD  704       // hg row stride (bf16); cols 682..703 zeroed (Kt for K=682)
#define F2LD  704       // fc2 weight ld (bf16), zero-padded
#define HBLD  1368      // hbuf row stride (bf16); 16B-aligned rows

typedef short          bf16x8 __attribute__((ext_vector_type(8)));
typedef unsigned short u16x8  __attribute__((ext_vector_type(8)));
typedef float          f32x4  __attribute__((ext_vector_type(4)));
typedef unsigned short u16;

static __device__ __forceinline__ float gelu_f(float x){ return 0.5f*x*(1.0f+erff(x*0.70710678118654752f)); }
static __device__ __forceinline__ u16 f2bf(float f){
  union { float f; unsigned u; } x; x.f = f;
  unsigned r = (x.u + 0x7FFFu + ((x.u >> 16) & 1u)) >> 16;
  return (u16)r;
}
static __device__ __forceinline__ float b2f(u16 u){
  union { unsigned u; float f; } x; x.u = ((unsigned)u) << 16;
  return x.f;
}
// async global->LDS, 16B per lane; lds dest = wave-uniform base + lane*16
static __device__ __forceinline__ void gld_lds16(const u16* g, u16* l){
  __builtin_amdgcn_global_load_lds((const __attribute__((address_space(1))) void*)g,
                                   (__attribute__((address_space(3))) void*)l, 16, 0, 0);
}
static __device__ __forceinline__ float rsum32(float v){
  #pragma unroll
  for (int m=16;m>0;m>>=1) v += __shfl_xor(v,m,32);
  return v;
}
static __device__ __forceinline__ float rsum64(float v){
  #pragma unroll
  for (int m=32;m>0;m>>=1) v += __shfl_xor(v,m,64);
  return v;
}
static __device__ __forceinline__ float rsum8(float v){
  v += __shfl_xor(v,1,64);
  v += __shfl_xor(v,2,64);
  v += __shfl_xor(v,4,64);
  return v;
}

// ---------------- all weight conversions, ONE launch ----------------
// seg6 now builds ltT[72][32] bf16: ltT[(h*9+j)*32+d] = lt[h][d][j]
__global__ __launch_bounds__(256) void cvt_all(const float* __restrict__ q_w,
                                               const float* __restrict__ kv_w,
                                               const float* __restrict__ sr_w,
                                               const float* __restrict__ pw,
                                               const float* __restrict__ f1w,
                                               const float* __restrict__ f2w,
                                               const float* __restrict__ lt,
                                               const float* __restrict__ dww,
                                               u16* __restrict__ wq,
                                               u16* __restrict__ wkv,
                                               u16* __restrict__ wsr,
                                               u16* __restrict__ wp,
                                               u16* __restrict__ wf1,
                                               u16* __restrict__ wf2,
                                               u16* __restrict__ ltT,
                                               float* __restrict__ dwwT){
  int t = blockIdx.x*256 + threadIdx.x;        // 0..16383
  int seg = blockIdx.y;
  const int NT = 64*256;
  if (seg == 0){            // q_w
    float4 v = *(const float4*)(q_w + (size_t)t*4);
    ushort4 o; o.x=f2bf(v.x); o.y=f2bf(v.y); o.z=f2bf(v.z); o.w=f2bf(v.w);
    *(ushort4*)(wq + (size_t)t*4) = o;
  } else if (seg == 1){     // kv_w
    for (int i=t; i<32768; i+=NT){
      float4 v = *(const float4*)(kv_w + (size_t)i*4);
      ushort4 o; o.x=f2bf(v.x); o.y=f2bf(v.y); o.z=f2bf(v.z); o.w=f2bf(v.w);
      *(ushort4*)(wkv + (size_t)i*4) = o;
    }
  } else if (seg == 2){     // sr_w
    float4 v = *(const float4*)(sr_w + (size_t)t*4);
    ushort4 o; o.x=f2bf(v.x); o.y=f2bf(v.y); o.z=f2bf(v.z); o.w=f2bf(v.w);
    *(ushort4*)(wsr + (size_t)t*4) = o;
  } else if (seg == 3){     // proj w
    float4 v = *(const float4*)(pw + (size_t)t*4);
    ushort4 o; o.x=f2bf(v.x); o.y=f2bf(v.y); o.z=f2bf(v.z); o.w=f2bf(v.w);
    *(ushort4*)(wp + (size_t)t*4) = o;
  } else if (seg == 4){     // f1w row-padded: 1408 rows x 256, src 1364 rows
    for (int i=t; i<360448; i+=NT){
      int r = i >> 8;
      wf1[i] = (r < 1364) ? f2bf(f1w[i]) : (u16)0;
    }
  } else if (seg == 5){     // f2w col-padded: 256 rows x 704, src K=682
    for (int i=t; i<256*F2LD; i+=NT){
      int r = i/F2LD, k = i - r*F2LD;
      wf2[i] = (k < HF_) ? f2bf(f2w[(size_t)r*HF_ + k]) : (u16)0;
    }
  } else if (seg == 6){     // ltT: 72 rows x 32
    for (int i=t; i<72*32; i+=NT){
      int r = i >> 5, d = i & 31;
      int h = r/9, j = r - h*9;
      ltT[i] = f2bf(lt[((size_t)(h*32 + d))*9 + j]);
    }
  } else {                  // dwwT
    for (int i=t; i<9*684; i+=NT){
      int l = i/684, f = i - l*684;
      dwwT[i] = (f < HF_) ? dww[(size_t)f*9 + l] : 0.f;
    }
  }
}

// ---------------- LayerNorm, 4 rows/block, float4 loads, wave-only reduce ------
__global__ __launch_bounds__(256) void ln4_kernel(const float* __restrict__ in,
                                                  const float* __restrict__ w,
                                                  const float* __restrict__ bsh,
                                                  u16* __restrict__ out){
  int t = threadIdx.x, wv = t>>6, l = t&63;
  int row = blockIdx.x*4 + wv;
  const float* rp = in + (size_t)row*C_ + l*4;
  float4 v = *(const float4*)rp;
  float s = v.x+v.y+v.z+v.w;
  float q = v.x*v.x+v.y*v.y+v.z*v.z+v.w*v.w;
  s = rsum64(s); q = rsum64(q);
  float m = s*(1.0f/C_);
  float var = q*(1.0f/C_)-m*m;
  float inv = rsqrtf(var+1e-5f);
  float4 wvv = *(const float4*)(w + l*4);
  float4 bvv = *(const float4*)(bsh + l*4);
  ushort4 o;
  o.x = f2bf((v.x-m)*inv*wvv.x + bvv.x);
  o.y = f2bf((v.y-m)*inv*wvv.y + bvv.y);
  o.z = f2bf((v.z-m)*inv*wvv.z + bvv.z);
  o.w = f2bf((v.w-m)*inv*wvv.w + bvv.w);
  *(ushort4*)(out + (size_t)row*C_ + l*4) = o;
}

// ---------------- bf16-in GEMM, 64x64 tile, BK=32 (reg staging; guarded) -------
template<int ACT, int RES, int OUTBF>
__global__ __launch_bounds__(256) void gemm64b(const u16* __restrict__ A, int lda,
                                               const u16* __restrict__ W, int ldw,
                                               const float* __restrict__ bias,
                                               const float* __restrict__ res,
                                               void* __restrict__ outv,
                                               int M, int Nt, int K){
  constexpr int LDT = 40;
  __shared__ u16 As[64*LDT];
  __shared__ u16 Bs[64*LDT];
  int tid = threadIdx.x, lane = tid & 63;
  int wave = tid >> 6;
  int m0 = blockIdx.x*64, n0 = blockIdx.y*64;
  int wm = (wave>>1)*32, wn = (wave&1)*32;
  f32x4 acc[2][2];
  #pragma unroll
  for (int i=0;i<2;i++)
    #pragma unroll
    for (int j=0;j<2;j++) acc[i][j] = (f32x4){0.f,0.f,0.f,0.f};

  const int Kt = (K + 31) & ~31;
  const int l15 = lane & 15, quad = lane >> 4;
  int r  = tid >> 2;
  int c8 = (tid & 3) * 8;

  for (int k0=0; k0<Kt; k0+=32){
    int gk = k0 + c8;
    u16x8 av = (u16x8){0,0,0,0,0,0,0,0};
    if (m0 + r < M && gk + 8 <= lda)
      av = *(const u16x8*)(A + (size_t)(m0+r)*lda + gk);
    *(u16x8*)(&As[r*LDT + c8]) = av;
    u16x8 bv = (u16x8){0,0,0,0,0,0,0,0};
    if (n0 + r < Nt && gk + 8 <= ldw)
      bv = *(const u16x8*)(W + (size_t)(n0+r)*ldw + gk);
    *(u16x8*)(&Bs[r*LDT + c8]) = bv;
    __syncthreads();
    bf16x8 af[2], bfr[2];
    #pragma unroll
    for (int mi=0;mi<2;mi++)
      af[mi] = *(bf16x8*)(&As[(wm + mi*16 + l15)*LDT + quad*8]);
    #pragma unroll
    for (int nj=0;nj<2;nj++)
      bfr[nj] = *(bf16x8*)(&Bs[(wn + nj*16 + l15)*LDT + quad*8]);
    #pragma unroll
    for (int mi=0;mi<2;mi++)
      #pragma unroll
      for (int nj=0;nj<2;nj++)
        acc[mi][nj] = __builtin_amdgcn_mfma_f32_16x16x32_bf16(af[mi], bfr[nj], acc[mi][nj], 0,0,0);
    __syncthreads();
  }
  int rbase = quad*4;
  #pragma unroll
  for (int nj=0;nj<2;nj++){
    int gc = n0 + wn + nj*16 + l15;
    if (gc >= Nt) continue;
    float bv = bias[gc];
    #pragma unroll
    for (int mi=0;mi<2;mi++){
      #pragma unroll
      for (int reg=0;reg<4;reg++){
        int gr = m0 + wm + mi*16 + rbase + reg;
        if (gr >= M) continue;
        float v = acc[mi][nj][reg] + bv;
        if (ACT==1) v = gelu_f(v);
        if (RES)   v += res[(size_t)gr*Nt + gc];
        if (OUTBF) ((u16*)outv)[(size_t)gr*Nt + gc] = f2bf(v);
        else       ((float*)outv)[(size_t)gr*Nt + gc] = v;
      }
    }
  }
}

// ---------------- 64x64 GEMM, reg staging, UNGUARDED, f32 out + residual -------
__global__ __launch_bounds__(256) void gemm64r(const u16* __restrict__ A, int lda,
                                               const u16* __restrict__ W, int ldw,
                                               const float* __restrict__ bias,
                                               const float* __restrict__ res,
                                               float* __restrict__ outv,
                                               int Nt, int Kt){
  constexpr int LDT = 40;
  __shared__ u16 As[64*LDT];
  __shared__ u16 Bs[64*LDT];
  int tid = threadIdx.x, lane = tid & 63;
  int wave = tid >> 6;
  int m0 = blockIdx.x*64, n0 = blockIdx.y*64;
  int wm = (wave>>1)*32, wn = (wave&1)*32;
  f32x4 acc[2][2];
  #pragma unroll
  for (int i=0;i<2;i++)
    #pragma unroll
    for (int j=0;j<2;j++) acc[i][j] = (f32x4){0.f,0.f,0.f,0.f};

  const int l15 = lane & 15, quad = lane >> 4;
  int r  = tid >> 2;
  int c8 = (tid & 3) * 8;
  const u16* ga = A + (size_t)(m0+r)*lda + c8;
  const u16* gb = W + (size_t)(n0+r)*ldw + c8;

  for (int k0=0; k0<Kt; k0+=32){
    *(u16x8*)(&As[r*LDT + c8]) = *(const u16x8*)(ga + k0);
    *(u16x8*)(&Bs[r*LDT + c8]) = *(const u16x8*)(gb + k0);
    __syncthreads();
    bf16x8 af[2], bfr[2];
    #pragma unroll
    for (int mi=0;mi<2;mi++)
      af[mi] = *(bf16x8*)(&As[(wm + mi*16 + l15)*LDT + quad*8]);
    #pragma unroll
    for (int nj=0;nj<2;nj++)
      bfr[nj] = *(bf16x8*)(&Bs[(wn + nj*16 + l15)*LDT + quad*8]);
    #pragma unroll
    for (int mi=0;mi<2;mi++)
      #pragma unroll
      for (int nj=0;nj<2;nj++)
        acc[mi][nj] = __builtin_amdgcn_mfma_f32_16x16x32_bf16(af[mi], bfr[nj], acc[mi][nj], 0,0,0);
    __syncthreads();
  }
  int rbase = quad*4;
  #pragma unroll
  for (int nj=0;nj<2;nj++){
    int gc = n0 + wn + nj*16 + l15;
    float bv = bias[gc];
    #pragma unroll
    for (int mi=0;mi<2;mi++){
      #pragma unroll
      for (int reg=0;reg<4;reg++){
        int gr = m0 + wm + mi*16 + rbase + reg;
        outv[(size_t)gr*Nt + gc] = acc[mi][nj][reg] + bv + res[(size_t)gr*Nt + gc];
      }
    }
  }
}

// ---------------- fused q/kv/sr 64x64 GEMM, reg staging, ONE launch ------------
__global__ __launch_bounds__(256) void gemm64f(const u16* __restrict__ A,
                                               const u16* __restrict__ W0,
                                               const u16* __restrict__ W1,
                                               const u16* __restrict__ W2,
                                               const float* __restrict__ b0,
                                               const float* __restrict__ b1,
                                               const float* __restrict__ b2,
                                               u16* __restrict__ o0,
                                               u16* __restrict__ o1,
                                               u16* __restrict__ o2){
  constexpr int LDT = 40;
  __shared__ u16 As[64*LDT];
  __shared__ u16 Bs[64*LDT];
  int tid = threadIdx.x, lane = tid & 63;
  int wave = tid >> 6;
  int m0 = blockIdx.x*64, y = blockIdx.y;
  const u16* Wp; const float* bp; u16* dst; int dld, dcol0; bool act = false;
  if (y < 4)      { Wp = W0 + (size_t)y*64*C_;      bp = b0 + y*64;      dst = o0; dld = 256; dcol0 = y*64; }
  else if (y < 12){ Wp = W1 + (size_t)(y-4)*64*C_;  bp = b1 + (y-4)*64;  dst = o1; dld = 512; dcol0 = (y-4)*64; }
  else            { Wp = W2 + (size_t)(y-12)*64*C_; bp = b2 + (y-12)*64; dst = o2; dld = 256; dcol0 = (y-12)*64; act = true; }
  int wm = (wave>>1)*32, wn = (wave&1)*32;
  f32x4 acc[2][2];
  #pragma unroll
  for (int i=0;i<2;i++)
    #pragma unroll
    for (int j=0;j<2;j++) acc[i][j] = (f32x4){0.f,0.f,0.f,0.f};

  const int l15 = lane & 15, quad = lane >> 4;
  int r  = tid >> 2;
  int c8 = (tid & 3) * 8;

  #pragma unroll 1
  for (int k0=0; k0<256; k0+=32){
    int gk = k0 + c8;
    *(u16x8*)(&As[r*LDT + c8]) = *(const u16x8*)(A  + (size_t)(m0+r)*C_ + gk);
    *(u16x8*)(&Bs[r*LDT + c8]) = *(const u16x8*)(Wp + (size_t)r*C_ + gk);
    __syncthreads();
    bf16x8 af[2], bfr[2];
    #pragma unroll
    for (int mi=0;mi<2;mi++)
      af[mi] = *(bf16x8*)(&As[(wm + mi*16 + l15)*LDT + quad*8]);
    #pragma unroll
    for (int nj=0;nj<2;nj++)
      bfr[nj] = *(bf16x8*)(&Bs[(wn + nj*16 + l15)*LDT + quad*8]);
    #pragma unroll
    for (int mi=0;mi<2;mi++)
      #pragma unroll
      for (int nj=0;nj<2;nj++)
        acc[mi][nj] = __builtin_amdgcn_mfma_f32_16x16x32_bf16(af[mi], bfr[nj], acc[mi][nj], 0,0,0);
    __syncthreads();
  }
  int rbase = quad*4;
  #pragma unroll
  for (int nj=0;nj<2;nj++){
    int cc = wn + nj*16 + l15;
    float bv = bp[cc];
    #pragma unroll
    for (int mi=0;mi<2;mi++){
      #pragma unroll
      for (int reg=0;reg<4;reg++){
        int gr = m0 + wm + mi*16 + rbase + reg;
        float v = acc[mi][nj][reg] + bv;
        if (act) v = gelu_f(v);
        dst[(size_t)gr*dld + dcol0 + cc] = f2bf(v);
      }
    }
  }
}

// ---------------- m97-structure GEMM, 128x128 tile, BK=32, gld_lds staging -----
template<int EPI>
__global__ __launch_bounds__(256) void gemm128t(const u16* __restrict__ A, int lda,
                                                const u16* __restrict__ W0,
                                                const float* __restrict__ b0,
                                                u16* __restrict__ o0,
                                                int M, int Nt, int K, int ldo){
  __shared__ u16 smem[8704];
  u16* As = smem;
  u16* Bs = smem + 4096;
  int tid = threadIdx.x, lane = tid & 63, wave = tid >> 6;
  int m0 = blockIdx.x*128, y = blockIdx.y;
  int wm = (wave>>1)*64, wn = (wave&1)*64;
  int l15 = lane & 15, quad = lane >> 4;

  const u16* Wp = W0 + (size_t)y*128*(size_t)lda;
  const float* bp = b0;
  u16* dstb = o0; int dld = ldo, dcol0 = y*128;

  f32x4 acc[4][4];
  #pragma unroll
  for (int i=0;i<4;i++)
    #pragma unroll
    for (int j=0;j<4;j++) acc[i][j] = (f32x4){0.f,0.f,0.f,0.f};

  const int Kt = (K + 31) & ~31;
  const u16* ga = A  + (size_t)(m0 + lane)*lda + wave*8;
  const u16* gb = Wp + (size_t)lane*lda + wave*8;
  u16* la = As + wave*1024;
  u16* lb = Bs + wave*1024;

  for (int k0=0; k0<Kt; k0+=32){
    gld_lds16(ga + k0,            la);
    gld_lds16(ga + 64*lda + k0,   la + 512);
    gld_lds16(gb + k0,            lb);
    gld_lds16(gb + 64*lda + k0,   lb + 512);
    __syncthreads();
    bf16x8 af[4], bfr[4];
    #pragma unroll
    for (int mi=0;mi<4;mi++)
      af[mi] = *(bf16x8*)(&As[quad*1024 + (wm + mi*16 + l15)*8]);
    #pragma unroll
    for (int nj=0;nj<4;nj++)
      bfr[nj] = *(bf16x8*)(&Bs[quad*1024 + (wn + nj*16 + l15)*8]);
    #pragma unroll
    for (int mi=0;mi<4;mi++)
      #pragma unroll
      for (int nj=0;nj<4;nj++)
        acc[mi][nj] = __builtin_amdgcn_mfma_f32_16x16x32_bf16(af[mi], bfr[nj], acc[mi][nj], 0,0,0);
    __syncthreads();
  }

  u16* Cs = smem;
  #pragma unroll
  for (int p=0;p<2;p++){
    if (wm == p*64){
      #pragma unroll
      for (int nj=0;nj<4;nj++){
        int cc = wn + nj*16 + l15;
        int gc = dcol0 + cc;
        float bv = (gc < Nt) ? bp[gc] : 0.f;
        #pragma unroll
        for (int mi=0;mi<4;mi++){
          #pragma unroll
          for (int reg=0;reg<4;reg++){
            int rr = mi*16 + quad*4 + reg;
            Cs[rr*136 + cc] = f2bf(acc[mi][nj][reg] + bv);
          }
        }
      }
    }
    __syncthreads();
    int r = tid >> 2, cb = (tid & 3)*32;
    int gr = m0 + p*64 + r;
    if (gr < M){
      u16* op = dstb + (size_t)gr*dld + dcol0;
      #pragma unroll
      for (int k=0;k<4;k++){
        int c0 = cb + k*8;
        if (dcol0 + c0 + 8 <= ldo)
          *(u16x8*)(op + c0) = *(u16x8*)&Cs[r*136 + c0];
      }
    }
    __syncthreads();
  }
}

// ---------------- merged (vectorized rows): qpost+knorm (4 rows/blk) | pool_ln ----
__global__ __launch_bounds__(256) void post1_kernel(u16* __restrict__ q,
                                                    const float* __restrict__ qe,
                                                    const float* __restrict__ temp,
                                                    const float* __restrict__ sls,
                                                    u16* __restrict__ qs_out,
                                                    u16* __restrict__ kv,
                                                    const u16* __restrict__ xsr,
                                                    const float* __restrict__ npw,
                                                    const float* __restrict__ npb,
                                                    u16* __restrict__ xpln){
  __shared__ float s1[4], s2[4];
  int bid = blockIdx.x, tid = threadIdx.x;
  if (bid < MROWS/4){
    int wv = tid>>6, l = tid&63;
    int row = bid*4 + wv;
    int c = l*4, h = l>>3;
    size_t idx = (size_t)row*C_ + c;
    ushort4 qv = *(const ushort4*)(q + idx);
    float v0=b2f(qv.x), v1=b2f(qv.y), v2=b2f(qv.z), v3=b2f(qv.w);
    float ss = rsum8(v0*v0+v1*v1+v2*v2+v3*v3);
    float inv = 1.0f / fmaxf(sqrtf(ss), 1e-12f);
    float qn0=v0*inv, qn1=v1*inv, qn2=v2*inv, qn3=v3*inv;
    ushort4 qo; qo.x=f2bf(qn0); qo.y=f2bf(qn1); qo.z=f2bf(qn2); qo.w=f2bf(qn3);
    *(ushort4*)(q + idx) = qo;
    float t  = temp[h];
    float sp = log1pf(expf(t));
    float scale = sp * sls[0];
    float4 qev = *(const float4*)(qe + c);
    ushort4 so;
    so.x = f2bf((qn0 + qev.x)*scale);
    so.y = f2bf((qn1 + qev.y)*scale);
    so.z = f2bf((qn2 + qev.z)*scale);
    so.w = f2bf((qn3 + qev.w)*scale);
    *(ushort4*)(qs_out + idx) = so;
    size_t kidx = (size_t)row*512 + c;
    ushort4 kvv = *(const ushort4*)(kv + kidx);
    float k0=b2f(kvv.x), k1=b2f(kvv.y), k2=b2f(kvv.z), k3=b2f(kvv.w);
    float ks = rsum8(k0*k0+k1*k1+k2*k2+k3*k3);
    float kinv = 1.0f / fmaxf(sqrtf(ks), 1e-12f);
    ushort4 ko; ko.x=f2bf(k0*kinv); ko.y=f2bf(k1*kinv); ko.z=f2bf(k2*kinv); ko.w=f2bf(k3*kinv);
    *(ushort4*)(kv + kidx) = ko;
  } else {
    int blk = bid - MROWS/4;          // 0..391
    int b = blk/PL_; int p = blk%PL_;
    int py = p/7, px = p%7;
    int o = tid;
    float s = 0.f;
    for (int iy=0;iy<8;iy++){
      const u16* rowp = xsr + ((size_t)(b*N_ + (py*8+iy)*WW + px*8))*C_ + o;
      #pragma unroll
      for (int ix=0;ix<8;ix++) s += b2f(rowp[(size_t)ix*C_]);
    }
    s *= (1.0f/64.0f);
    float su = rsum64(s), sq = rsum64(s*s);
    if ((o&63)==0){ s1[o>>6]=su; s2[o>>6]=sq; }
    __syncthreads();
    float ts=s1[0]+s1[1]+s1[2]+s1[3];
    float tq=s2[0]+s2[1]+s2[2]+s2[3];
    float m = ts*(1.0f/256.0f), var = tq*(1.0f/256.0f)-m*m;
    float inv = rsqrtf(var+1e-5f);
    xpln[(size_t)blk*C_+o] = f2bf((s-m)*inv*npw[o]+npb[o]);
  }
}

// ---------------- merged: kvp2 knorm (blocks 0..391) | cpb MLP (392..1415) -----
__global__ __launch_bounds__(256) void misc2_kernel(u16* __restrict__ kvp2,
                                                    const float* __restrict__ rct,
                                                    const float* __restrict__ w1,
                                                    const float* __restrict__ b1,
                                                    const float* __restrict__ w2,
                                                    const float* __restrict__ b2v,
                                                    float* __restrict__ cpb){
  __shared__ float r[512];
  int bid = blockIdx.x, tid = threadIdx.x;
  if (bid < B_*PL_){
    int row = bid;
    size_t idx = (size_t)row*512 + tid;
    float v = b2f(kvp2[idx]);
    float ss = rsum32(v*v);
    kvp2[idx] = f2bf(v / fmaxf(sqrtf(ss), 1e-12f));
  } else {
    int t = bid - B_*PL_;             // 0..1023
    float c0 = rct[t*2], c1 = rct[t*2+1];
    for (int j=tid;j<512;j+=256){
      float v = c0*w1[j*2] + c1*w1[j*2+1] + b1[j];
      r[j] = fmaxf(v, 0.f);
    }
    __syncthreads();
    int h = tid>>5, lane = tid&31;
    float s = 0.f;
    for (int j=lane;j<512;j+=32) s += r[j]*w2[h*512+j];
    s = rsum32(s);
    if (lane==0) cpb[t*8+h] = s + b2v[h];
  }
}

// ---------------- pooled attention logits via MFMA -> attn[row*392 + h*49 + p] ----
__global__ __launch_bounds__(256) void attn_pool_mfma(const u16* __restrict__ qs,
                                                      const u16* __restrict__ kvp2,
                                                      const float* __restrict__ cpb,
                                                      const int* __restrict__ ridx,
                                                      float* __restrict__ attn){
  int tid = threadIdx.x, lane = tid & 63, wave = tid >> 6;
  int l15 = lane & 15, quad = lane >> 4;
  int bh = blockIdx.y, b = bh >> 3, h = bh & 7;
  int n0 = (blockIdx.x*4 + wave)*16;
  bf16x8 af = *(const bf16x8*)(qs + ((size_t)(b*N_ + n0 + l15)*C_ + h*32 + quad*8));
  f32x4 acc[4];
  #pragma unroll
  for (int nj=0;nj<4;nj++){
    int p = nj*16 + l15;
    bf16x8 bfr = (bf16x8){0,0,0,0,0,0,0,0};
    if (p < PL_)
      bfr = *(const bf16x8*)(kvp2 + ((size_t)(b*PL_ + p)*512 + h*32 + quad*8));
    f32x4 z = (f32x4){0.f,0.f,0.f,0.f};
    acc[nj] = __builtin_amdgcn_mfma_f32_16x16x32_bf16(af, bfr, z, 0,0,0);
  }
  #pragma unroll
  for (int nj=0;nj<4;nj++){
    int p = nj*16 + l15;
    if (p >= PL_) continue;
    #pragma unroll
    for (int reg=0;reg<4;reg++){
      int n = n0 + quad*4 + reg;
      float bias = cpb[ridx[(size_t)n*PL_ + p]*8 + h];
      attn[(size_t)(b*N_ + n)*392 + h*49 + p] = acc[nj][reg] + bias;
    }
  }
}

// ---------------- xout_v6: local logits + qlt in-kernel, pooled from attn buffer ----
// Lane (h=l>>3, k=l&7) owns logits j=k+8i. Local j<9 computed in VALU from
// qsc.K-neighbor (+rpb); matching qlt = qn.ltT[h*9+j] + lb computed alongside.
// Pooled j>=9 read from 49-f32 attn rows. Softmax + PV identical to v4.
__global__ __launch_bounds__(256) void xout_v6(const u16* __restrict__ qn,
                                               const u16* __restrict__ qsc,
                                               const float* __restrict__ attnp,
                                               const u16* __restrict__ kv,
                                               const u16* __restrict__ kvp2,
                                               const float* __restrict__ rpb,
                                               const u16* __restrict__ ltT,
                                               const float* __restrict__ lb,
                                               u16* __restrict__ out){
  __shared__ float coef[4][472];
  int t = threadIdx.x, w = t>>6, l = t&63;
  int row = blockIdx.x*4 + w;
  int b = row / N_, n = row - b*N_;
  int y = n / WW, x = n - y*WW;
  // stage pooled logits into coef slots [h*58 + 9 + p]
  const float* arow = attnp + (size_t)row*392;
  for (int i=l; i<392; i+=64){
    int h2 = i/49, p = i - h2*49;
    coef[w][h2*58 + 9 + p] = arow[i];
  }
  int h = l>>3, k = l&7;
  // load q_scaled + q_norm head slices (32 each)
  float qs_[32], qn_[32];
  const u16* qsp = qsc + (size_t)row*C_ + h*32;
  const u16* qnp = qn  + (size_t)row*C_ + h*32;
  #pragma unroll
  for (int j=0;j<4;j++){
    u16x8 v1 = *(const u16x8*)(qsp + j*8);
    u16x8 v2 = *(const u16x8*)(qnp + j*8);
    #pragma unroll
    for (int e8=0;e8<8;e8++){ qs_[j*8+e8] = b2f(v1[e8]); qn_[j*8+e8] = b2f(v2[e8]); }
  }
  // local logit j=k (all lanes) and j=8 (k==0 only), plus qlt terms
  float e0, e1loc = 0.f, ql0, ql1 = 0.f;
  {
    int j = k;
    int yy = y + j/3 - 1, xx = x + j%3 - 1;
    float s = 0.f;
    if (yy>=0 && yy<HH && xx>=0 && xx<WW){
      const u16* kp = kv + ((size_t)(b*N_ + yy*WW + xx))*512 + h*32;
      #pragma unroll
      for (int jj=0;jj<4;jj++){
        u16x8 kw = *(const u16x8*)(kp + jj*8);
        #pragma unroll
        for (int ee=0;ee<8;ee++) s = fmaf(qs_[jj*8+ee], b2f(kw[ee]), s);
      }
    }
    e0 = s + rpb[h*9+j];
    float d = lb[h*9+j];
    const u16* lp = ltT + (size_t)(h*9+j)*32;
    #pragma unroll
    for (int jj=0;jj<4;jj++){
      u16x8 lw = *(const u16x8*)(lp + jj*8);
      #pragma unroll
      for (int ee=0;ee<8;ee++) d = fmaf(qn_[jj*8+ee], b2f(lw[ee]), d);
    }
    ql0 = d;
  }
  if (k == 0){
    int yy = y + 1, xx = x + 1;   // j=8 -> dy=1, dx=1
    float s = 0.f;
    if (yy < HH && xx < WW){
      const u16* kp = kv + ((size_t)(b*N_ + yy*WW + xx))*512 + h*32;
      #pragma unroll
      for (int jj=0;jj<4;jj++){
        u16x8 kw = *(const u16x8*)(kp + jj*8);
        #pragma unroll
        for (int ee=0;ee<8;ee++) s = fmaf(qs_[jj*8+ee], b2f(kw[ee]), s);
      }
    }
    e1loc = s + rpb[h*9+8];
    float d = lb[h*9+8];
    const u16* lp = ltT + (size_t)(h*9+8)*32;
    #pragma unroll
    for (int jj=0;jj<4;jj++){
      u16x8 lw = *(const u16x8*)(lp + jj*8);
      #pragma unroll
      for (int ee=0;ee<8;ee++) d = fmaf(qn_[jj*8+ee], b2f(lw[ee]), d);
    }
    ql1 = d;
  }
  __syncthreads();   // pooled stage complete
  float* ch = &coef[w][h*58];
  float e[8];
  e[0] = e0;
  e[1] = (k==0) ? e1loc : ch[k+8];
  #pragma unroll
  for (int i=2;i<8;i++){
    int j = k + i*8;
    e[i] = (j<58) ? ch[j] : -1e30f;
  }
  float mx = -1e30f;
  #pragma unroll
  for (int i=0;i<8;i++) mx = fmaxf(mx, e[i]);
  mx = fmaxf(mx, __shfl_xor(mx,1,64));
  mx = fmaxf(mx, __shfl_xor(mx,2,64));
  mx = fmaxf(mx, __shfl_xor(mx,4,64));
  float s = 0.f;
  #pragma unroll
  for (int i=0;i<8;i++){
    int j = k + i*8;
    if (j<58){ e[i] = expf(e[i]-mx); s += e[i]; }
  }
  s += __shfl_xor(s,1,64);
  s += __shfl_xor(s,2,64);
  s += __shfl_xor(s,4,64);
  float inv = 1.f/s;
  #pragma unroll
  for (int i=0;i<8;i++){
    int j = k + i*8;
    if (j<58){
      float v = e[i]*inv;
      if (i==0) v += ql0;
      if (i==1 && k==0) v += ql1;
      ch[j] = v;
    }
  }
  __syncthreads();
  // PV
  int c = l*4;
  float a0=0.f, a1=0.f, a2=0.f, a3=0.f;
  #pragma unroll
  for (int lw=0; lw<9; lw++){
    int yy = y + lw/3 - 1, xx = x + lw%3 - 1;
    if (yy>=0 && yy<HH && xx>=0 && xx<WW){
      ushort4 vv = *(const ushort4*)(kv + ((size_t)(b*N_ + yy*WW + xx))*512 + 256 + c);
      float cf = ch[lw];
      a0 = fmaf(cf, b2f(vv.x), a0);
      a1 = fmaf(cf, b2f(vv.y), a1);
      a2 = fmaf(cf, b2f(vv.z), a2);
      a3 = fmaf(cf, b2f(vv.w), a3);
    }
  }
  const u16* pb = kvp2 + (size_t)b*PL_*512 + 256 + c;
  #pragma unroll 7
  for (int p=0;p<49;p++){
    ushort4 vv = *(const ushort4*)(pb + (size_t)p*512);
    float cf = ch[9+p];
    a0 = fmaf(cf, b2f(vv.x), a0);
    a1 = fmaf(cf, b2f(vv.y), a1);
    a2 = fmaf(cf, b2f(vv.z), a2);
    a3 = fmaf(cf, b2f(vv.w), a3);
  }
  ushort4 o; o.x=f2bf(a0); o.y=f2bf(a1); o.z=f2bf(a2); o.w=f2bf(a3);
  *(ushort4*)(out + (size_t)row*C_ + c) = o;
}

// ---------------- depthwise 3x3 + gelu gate, 8 ch/thread, XCD-confined ----------------
__global__ __launch_bounds__(256) void dwconv_v4(const u16* __restrict__ hsrc,
                                                 const float* __restrict__ dwwT,
                                                 const float* __restrict__ dwb,
                                                 u16* __restrict__ hg){
  int b = blockIdx.x;
  int idx = blockIdx.y*256 + threadIdx.x;
  if (idx >= N_*86) return;
  int n = idx/86, g = idx - n*86;
  int pix = b*N_ + n;
  int y = n / WW, x = n - y*WW;
  const u16* hb = hsrc + (size_t)b*N_*HBLD;
  if (g < 85){
    int f = g*8;
    float s[8];
    #pragma unroll
    for (int e=0;e<8;e++) s[e] = dwb[f+e];
    #pragma unroll
    for (int l=0;l<9;l++){
      int yy = y + l/3 - 1, xx = x + l%3 - 1;
      if (yy>=0 && yy<HH && xx>=0 && xx<WW){
        u16x8 hv = *(const u16x8*)(hb + (size_t)(yy*WW+xx)*HBLD + f);
        const float* wv = dwwT + (size_t)l*684 + f;
        #pragma unroll
        for (int e=0;e<8;e++) s[e] = fmaf(b2f(hv[e]), wv[e], s[e]);
      }
    }
    const u16* vp = hsrc + (size_t)pix*HBLD + HF_ + f;
    u16 ov[8];
    #pragma unroll
    for (int e=0;e<8;e++) ov[e] = f2bf(gelu_f(s[e]) * b2f(vp[e]));
    *(u16x8*)(hg + (size_t)pix*HGLD + f) = *(u16x8*)ov;
  } else {
    float r[2];
    #pragma unroll
    for (int c=0;c<2;c++){
      int ff = 680 + c;
      float s = dwb[ff];
      #pragma unroll
      for (int l=0;l<9;l++){
        int yy = y + l/3 - 1, xx = x + l%3 - 1;
        if (yy>=0 && yy<HH && xx>=0 && xx<WW)
          s += b2f(hb[(size_t)(yy*WW+xx)*HBLD + ff]) * dwwT[(size_t)l*684 + ff];
      }
      r[c] = gelu_f(s) * b2f(hsrc[(size_t)pix*HBLD + HF_ + ff]);
    }
    u16* hp = hg + (size_t)pix*HGLD;
    ushort4 o1; o1.x = f2bf(r[0]); o1.y = f2bf(r[1]); o1.z = 0; o1.w = 0;
    *(ushort4*)(hp + 680) = o1;
    ushort4 z4 = {0,0,0,0};
    *(ushort4*)(hp + 684) = z4;
    *(ushort4*)(hp + 688) = z4;
    *(ushort4*)(hp + 692) = z4;
    *(ushort4*)(hp + 696) = z4;
    *(ushort4*)(hp + 700) = z4;
  }
}

extern "C" void kernel_launch(void* const* d_in, const int* in_sizes, int n_in,
                              void* d_out, int out_size, void* d_ws, size_t ws_size,
                              hipStream_t stream) {
  const float* x    = (const float*)d_in[0];
  const float* rct  = (const float*)d_in[1];
  const float* sls  = (const float*)d_in[2];
  const float* n1w  = (const float*)d_in[3];
  const float* n1b  = (const float*)d_in[4];
  const float* q_w  = (const float*)d_in[5];
  const float* q_b  = (const float*)d_in[6];
  const float* kv_w = (const float*)d_in[7];
  const float* kv_b = (const float*)d_in[8];
  const float* temp = (const float*)d_in[9];
  const float* qe   = (const float*)d_in[10];
  const float* rpb  = (const float*)d_in[11];
  const float* lt   = (const float*)d_in[12];
  const float* lb   = (const float*)d_in[13];
  const float* sr_w = (const float*)d_in[14];
  const float* sr_b = (const float*)d_in[15];
  const float* npw  = (const float*)d_in[16];
  const float* npb  = (const float*)d_in[17];
  const float* c1w  = (const float*)d_in[18];
  const float* c1b  = (const float*)d_in[19];
  const float* c2w  = (const float*)d_in[20];
  const float* c2b  = (const float*)d_in[21];
  const float* pw   = (const float*)d_in[22];
  const float* pb   = (const float*)d_in[23];
  const float* n2w  = (const float*)d_in[24];
  const float* n2b  = (const float*)d_in[25];
  const float* f1w  = (const float*)d_in[26];
  const float* f1b  = (const float*)d_in[27];
  const float* dww  = (const float*)d_in[28];
  const float* dwb  = (const float*)d_in[29];
  const float* f2w  = (const float*)d_in[30];
  const float* f2bb = (const float*)d_in[31];
  const int*  ridx  = (const int*)d_in[32];
  float* outp = (float*)d_out;

  char* ws = (char*)d_ws;
  constexpr size_t SZ_BNC2 = (size_t)MROWS*C_*2;
  constexpr size_t SZ_KV2  = (size_t)MROWS*512*2;
  constexpr size_t SZ_ATTN = (size_t)MROWS*464*4;
  size_t o_xn   = 0;
  size_t o_qn   = o_xn   + SZ_BNC2;
  size_t o_qs   = o_qn   + SZ_BNC2;
  size_t o_kv   = o_qs   + SZ_BNC2;
  size_t o_attn = o_kv   + SZ_KV2;
  size_t o_xsr  = o_attn + SZ_ATTN;
  size_t o_xpln = o_xsr  + SZ_BNC2;
  size_t o_kvp2 = o_xpln + (size_t)B_*PL_*C_*2;
  size_t o_cpb  = o_kvp2 + (size_t)B_*PL_*512*2;
  size_t o_outb = o_cpb  + (size_t)1024*8*4;
  size_t o_x2   = o_outb + SZ_BNC2;
  size_t o_qlt  = o_x2   + (size_t)MROWS*C_*4;
  size_t o_wq   = o_qlt  + (size_t)MROWS*72*4;
  size_t o_wkv  = o_wq   + (size_t)65536*2;
  size_t o_wsr  = o_wkv  + (size_t)131072*2;
  size_t o_wp   = o_wsr  + (size_t)65536*2;
  size_t o_wf1  = o_wp   + (size_t)65536*2;
  size_t o_wf2  = o_wf1  + (size_t)360448*2;     // 1408 rows x 256 (row-padded)
  size_t o_w72  = o_wf2  + (size_t)256*F2LD*2;
  size_t o_dwwT = o_w72  + (size_t)72*256*2;
  size_t o_h    = o_kv;
  size_t o_hg   = 0;

  u16*   xn   = (u16*)(ws + o_xn);
  u16*   qbuf = (u16*)(ws + o_qn);
  u16*   qsc  = (u16*)(ws + o_qs);
  u16*   kv   = (u16*)(ws + o_kv);
  float* attn = (float*)(ws + o_attn);
  u16*   xsr  = (u16*)(ws + o_xsr);
  u16*   xpln = (u16*)(ws + o_xpln);
  u16*   kvp2 = (u16*)(ws + o_kvp2);
  float* cpb  = (float*)(ws + o_cpb);
  u16*   outb = (u16*)(ws + o_outb);
  float* x2   = (float*)(ws + o_x2);
  u16*   wq   = (u16*)(ws + o_wq);
  u16*   wkv  = (u16*)(ws + o_wkv);
  u16*   wsr  = (u16*)(ws + o_wsr);
  u16*   wp   = (u16*)(ws + o_wp);
  u16*   wf1  = (u16*)(ws + o_wf1);
  u16*   wf2  = (u16*)(ws + o_wf2);
  u16*   ltT  = (u16*)(ws + o_w72);
  float* dwwT = (float*)(ws + o_dwwT);
  u16*   hbuf = (u16*)(ws + o_h);
  u16*   hg   = (u16*)(ws + o_hg);

  // 0. all weight conversions, one launch
  cvt_all<<<dim3(64,8), 256, 0, stream>>>(q_w, kv_w, sr_w, pw, f1w, f2w, lt, dww,
                                          wq, wkv, wsr, wp, wf1, wf2, ltT, dwwT);
  // 1. xn = LN(x) -> bf16 (vectorized, 4 rows/block)
  ln4_kernel<<<MROWS/4, 256, 0, stream>>>(x, n1w, n1b, xn);
  // 2-6. fused q / kv / sr projections, one launch, reg-staged 64-tile (max TLP)
  gemm64f<<<dim3(392,16), 256, 0, stream>>>(xn, wq, wkv, wsr, q_b, kv_b, sr_b,
                                            qbuf, kv, xsr);
  // 4+5+7. q_norm + q_scaled + k l2norm (4 rows/blk, vectorized) | pool+LN (merged)
  post1_kernel<<<MROWS/4 + B_*PL_, 256, 0, stream>>>(qbuf, qe, temp, sls, qsc, kv,
                                                     xsr, npw, npb, xpln);
  // 8. kvp2 = xpln @ kv_w^T + kv_b -> bf16 (guarded small GEMM)
  gemm64b<0,0,1><<<dim3(7,8), 256, 0, stream>>>(xpln, C_, wkv, C_, kv_b, nullptr, kvp2, B_*PL_, 512, 256);
  // 9+10. kvp2 knorm | CPB MLP (merged)
  misc2_kernel<<<B_*PL_ + 1024, 256, 0, stream>>>(kvp2, rct, c1w, c1b, c2w, c2b, cpb);
  // 12. pooled attention logits via MFMA -> 49-f32 rows
  attn_pool_mfma<<<dim3(49,64), 256, 0, stream>>>(qsc, kvp2, cpb, ridx, attn);
  // 11+13+14. local logits + qlt + softmax + x_local + x_pool -> outb bf16
  xout_v6<<<MROWS/4, 256, 0, stream>>>(qbuf, qsc, attn, kv, kvp2, rpb, ltT, lb, outb);
  // 15. x2 = x + outb @ proj_w^T + proj_b -> f32 (reg-staged, unguarded)
  gemm64r<<<dim3(392,4), 256, 0, stream>>>(outb, C_, wp, C_, pb, x, x2, 256, 256);
  // 16. xn2 = LN(x2) -> bf16 (vectorized, reuses xn)
  ln4_kernel<<<MROWS/4, 256, 0, stream>>>(x2, n2w, n2b, xn);
  // 17. h = xn2 @ fc1_w^T + fc1_b -> bf16 (ldo=HBLD, m97-structure 128-tile)
  gemm128t<0><<<dim3(196,11), 256, 0, stream>>>(xn, C_, wf1, f1b, hbuf, MROWS, 1364, 256, HBLD);
  // 18. hg = gelu(dwconv(h1)+dwb) * v -> bf16 (8 ch/thread, XCD-confined)
  dwconv_v4<<<dim3(8, (N_*86+255)/256), 256, 0, stream>>>(hbuf, dwwT, dwb, hg);
  // 19. out = x2 + hg @ fc2_w^T + fc2_b -> f32 (reg-staged, unguarded, K=704 padded)
  gemm64r<<<dim3(392,4), 256, 0, stream>>>(hg, HGLD, wf2, F2LD, f2bb, x2, outp, 256, 704);
}

// Round 13
// 497.338 us; speedup vs baseline: 1.0320x; 1.0320x over previous
//
#include <hip/hip_runtime.h>
#include <math.h>

#define B_   8
#define N_   3136
#define C_   256
#define NH_  8
#define HD_  32
#define LL_  9
#define PL_  49
#define HF_  682
#define HH   56
#define WW   56
#define MROWS (B_*N_)   // 25088
#define HGLD  704       // hg row stride (bf16); cols 682..703 zeroed (Kt for K=682)
#define F2LD  704       // fc2 weight ld (bf16), zero-padded
#define HBLD  1368      // hbuf row stride (bf16); 16B-aligned rows

typedef short          bf16x8 __attribute__((ext_vector_type(8)));
typedef unsigned short u16x8  __attribute__((ext_vector_type(8)));
typedef float          f32x4  __attribute__((ext_vector_type(4)));
typedef unsigned short u16;

static __device__ __forceinline__ float gelu_f(float x){ return 0.5f*x*(1.0f+erff(x*0.70710678118654752f)); }
static __device__ __forceinline__ u16 f2bf(float f){
  union { float f; unsigned u; } x; x.f = f;
  unsigned r = (x.u + 0x7FFFu + ((x.u >> 16) & 1u)) >> 16;
  return (u16)r;
}
static __device__ __forceinline__ float b2f(u16 u){
  union { unsigned u; float f; } x; x.u = ((unsigned)u) << 16;
  return x.f;
}
// async global->LDS, 16B per lane; lds dest = wave-uniform base + lane*16
static __device__ __forceinline__ void gld_lds16(const u16* g, u16* l){
  __builtin_amdgcn_global_load_lds((const __attribute__((address_space(1))) void*)g,
                                   (__attribute__((address_space(3))) void*)l, 16, 0, 0);
}
static __device__ __forceinline__ float rsum32(float v){
  #pragma unroll
  for (int m=16;m>0;m>>=1) v += __shfl_xor(v,m,32);
  return v;
}
static __device__ __forceinline__ float rsum64(float v){
  #pragma unroll
  for (int m=32;m>0;m>>=1) v += __shfl_xor(v,m,64);
  return v;
}
static __device__ __forceinline__ float rsum8(float v){
  v += __shfl_xor(v,1,64);
  v += __shfl_xor(v,2,64);
  v += __shfl_xor(v,4,64);
  return v;
}

// ---------------- all weight conversions, ONE launch ----------------
__global__ __launch_bounds__(256) void cvt_all(const float* __restrict__ q_w,
                                               const float* __restrict__ kv_w,
                                               const float* __restrict__ sr_w,
                                               const float* __restrict__ pw,
                                               const float* __restrict__ f1w,
                                               const float* __restrict__ f2w,
                                               const float* __restrict__ lt,
                                               const float* __restrict__ dww,
                                               u16* __restrict__ wq,
                                               u16* __restrict__ wkv,
                                               u16* __restrict__ wsr,
                                               u16* __restrict__ wp,
                                               u16* __restrict__ wf1,
                                               u16* __restrict__ wf2,
                                               u16* __restrict__ w72,
                                               float* __restrict__ dwwT){
  int t = blockIdx.x*256 + threadIdx.x;        // 0..16383
  int seg = blockIdx.y;
  const int NT = 64*256;
  if (seg == 0){            // q_w
    float4 v = *(const float4*)(q_w + (size_t)t*4);
    ushort4 o; o.x=f2bf(v.x); o.y=f2bf(v.y); o.z=f2bf(v.z); o.w=f2bf(v.w);
    *(ushort4*)(wq + (size_t)t*4) = o;
  } else if (seg == 1){     // kv_w
    for (int i=t; i<32768; i+=NT){
      float4 v = *(const float4*)(kv_w + (size_t)i*4);
      ushort4 o; o.x=f2bf(v.x); o.y=f2bf(v.y); o.z=f2bf(v.z); o.w=f2bf(v.w);
      *(ushort4*)(wkv + (size_t)i*4) = o;
    }
  } else if (seg == 2){     // sr_w
    float4 v = *(const float4*)(sr_w + (size_t)t*4);
    ushort4 o; o.x=f2bf(v.x); o.y=f2bf(v.y); o.z=f2bf(v.z); o.w=f2bf(v.w);
    *(ushort4*)(wsr + (size_t)t*4) = o;
  } else if (seg == 3){     // proj w
    float4 v = *(const float4*)(pw + (size_t)t*4);
    ushort4 o; o.x=f2bf(v.x); o.y=f2bf(v.y); o.z=f2bf(v.z); o.w=f2bf(v.w);
    *(ushort4*)(wp + (size_t)t*4) = o;
  } else if (seg == 4){     // f1w row-padded: 1408 rows x 256, src 1364 rows
    for (int i=t; i<360448; i+=NT){
      int r = i >> 8;
      wf1[i] = (r < 1364) ? f2bf(f1w[i]) : (u16)0;
    }
  } else if (seg == 5){     // f2w col-padded: 256 rows x 704, src K=682
    for (int i=t; i<256*F2LD; i+=NT){
      int r = i/F2LD, k = i - r*F2LD;
      wf2[i] = (k < HF_) ? f2bf(f2w[(size_t)r*HF_ + k]) : (u16)0;
    }
  } else if (seg == 6){     // w72
    for (int i=t; i<72*256; i+=NT){
      int r = i >> 8, c = i & 255;
      int h = r/9, l = r - h*9;
      w72[i] = ((c>>5) == h) ? f2bf(lt[((size_t)(h*32 + (c&31)))*9 + l]) : (u16)0;
    }
  } else {                  // dwwT
    for (int i=t; i<9*684; i+=NT){
      int l = i/684, f = i - l*684;
      dwwT[i] = (f < HF_) ? dww[(size_t)f*9 + l] : 0.f;
    }
  }
}

// ---------------- LayerNorm, 4 rows/block, float4 loads, wave-only reduce ------
__global__ __launch_bounds__(256) void ln4_kernel(const float* __restrict__ in,
                                                  const float* __restrict__ w,
                                                  const float* __restrict__ bsh,
                                                  u16* __restrict__ out){
  int t = threadIdx.x, wv = t>>6, l = t&63;
  int row = blockIdx.x*4 + wv;
  const float* rp = in + (size_t)row*C_ + l*4;
  float4 v = *(const float4*)rp;
  float s = v.x+v.y+v.z+v.w;
  float q = v.x*v.x+v.y*v.y+v.z*v.z+v.w*v.w;
  s = rsum64(s); q = rsum64(q);
  float m = s*(1.0f/C_);
  float var = q*(1.0f/C_)-m*m;
  float inv = rsqrtf(var+1e-5f);
  float4 wvv = *(const float4*)(w + l*4);
  float4 bvv = *(const float4*)(bsh + l*4);
  ushort4 o;
  o.x = f2bf((v.x-m)*inv*wvv.x + bvv.x);
  o.y = f2bf((v.y-m)*inv*wvv.y + bvv.y);
  o.z = f2bf((v.z-m)*inv*wvv.z + bvv.z);
  o.w = f2bf((v.w-m)*inv*wvv.w + bvv.w);
  *(ushort4*)(out + (size_t)row*C_ + l*4) = o;
}

// ---------------- bf16-in GEMM, 64x64 tile, BK=32 (reg staging; guarded) -------
template<int ACT, int RES, int OUTBF>
__global__ __launch_bounds__(256) void gemm64b(const u16* __restrict__ A, int lda,
                                               const u16* __restrict__ W, int ldw,
                                               const float* __restrict__ bias,
                                               const float* __restrict__ res,
                                               void* __restrict__ outv,
                                               int M, int Nt, int K){
  constexpr int LDT = 40;
  __shared__ u16 As[64*LDT];
  __shared__ u16 Bs[64*LDT];
  int tid = threadIdx.x, lane = tid & 63;
  int wave = tid >> 6;
  int m0 = blockIdx.x*64, n0 = blockIdx.y*64;
  int wm = (wave>>1)*32, wn = (wave&1)*32;
  f32x4 acc[2][2];
  #pragma unroll
  for (int i=0;i<2;i++)
    #pragma unroll
    for (int j=0;j<2;j++) acc[i][j] = (f32x4){0.f,0.f,0.f,0.f};

  const int Kt = (K + 31) & ~31;
  const int l15 = lane & 15, quad = lane >> 4;
  int r  = tid >> 2;
  int c8 = (tid & 3) * 8;

  for (int k0=0; k0<Kt; k0+=32){
    int gk = k0 + c8;
    u16x8 av = (u16x8){0,0,0,0,0,0,0,0};
    if (m0 + r < M && gk + 8 <= lda)
      av = *(const u16x8*)(A + (size_t)(m0+r)*lda + gk);
    *(u16x8*)(&As[r*LDT + c8]) = av;
    u16x8 bv = (u16x8){0,0,0,0,0,0,0,0};
    if (n0 + r < Nt && gk + 8 <= ldw)
      bv = *(const u16x8*)(W + (size_t)(n0+r)*ldw + gk);
    *(u16x8*)(&Bs[r*LDT + c8]) = bv;
    __syncthreads();
    bf16x8 af[2], bfr[2];
    #pragma unroll
    for (int mi=0;mi<2;mi++)
      af[mi] = *(bf16x8*)(&As[(wm + mi*16 + l15)*LDT + quad*8]);
    #pragma unroll
    for (int nj=0;nj<2;nj++)
      bfr[nj] = *(bf16x8*)(&Bs[(wn + nj*16 + l15)*LDT + quad*8]);
    #pragma unroll
    for (int mi=0;mi<2;mi++)
      #pragma unroll
      for (int nj=0;nj<2;nj++)
        acc[mi][nj] = __builtin_amdgcn_mfma_f32_16x16x32_bf16(af[mi], bfr[nj], acc[mi][nj], 0,0,0);
    __syncthreads();
  }
  int rbase = quad*4;
  #pragma unroll
  for (int nj=0;nj<2;nj++){
    int gc = n0 + wn + nj*16 + l15;
    if (gc >= Nt) continue;
    float bv = bias[gc];
    #pragma unroll
    for (int mi=0;mi<2;mi++){
      #pragma unroll
      for (int reg=0;reg<4;reg++){
        int gr = m0 + wm + mi*16 + rbase + reg;
        if (gr >= M) continue;
        float v = acc[mi][nj][reg] + bv;
        if (ACT==1) v = gelu_f(v);
        if (RES)   v += res[(size_t)gr*Nt + gc];
        if (OUTBF) ((u16*)outv)[(size_t)gr*Nt + gc] = f2bf(v);
        else       ((float*)outv)[(size_t)gr*Nt + gc] = v;
      }
    }
  }
}

// ---------------- 64x64 GEMM, reg staging, UNGUARDED, f32 out + residual -------
__global__ __launch_bounds__(256) void gemm64r(const u16* __restrict__ A, int lda,
                                               const u16* __restrict__ W, int ldw,
                                               const float* __restrict__ bias,
                                               const float* __restrict__ res,
                                               float* __restrict__ outv,
                                               int Nt, int Kt){
  constexpr int LDT = 40;
  __shared__ u16 As[64*LDT];
  __shared__ u16 Bs[64*LDT];
  int tid = threadIdx.x, lane = tid & 63;
  int wave = tid >> 6;
  int m0 = blockIdx.x*64, n0 = blockIdx.y*64;
  int wm = (wave>>1)*32, wn = (wave&1)*32;
  f32x4 acc[2][2];
  #pragma unroll
  for (int i=0;i<2;i++)
    #pragma unroll
    for (int j=0;j<2;j++) acc[i][j] = (f32x4){0.f,0.f,0.f,0.f};

  const int l15 = lane & 15, quad = lane >> 4;
  int r  = tid >> 2;
  int c8 = (tid & 3) * 8;
  const u16* ga = A + (size_t)(m0+r)*lda + c8;
  const u16* gb = W + (size_t)(n0+r)*ldw + c8;

  for (int k0=0; k0<Kt; k0+=32){
    *(u16x8*)(&As[r*LDT + c8]) = *(const u16x8*)(ga + k0);
    *(u16x8*)(&Bs[r*LDT + c8]) = *(const u16x8*)(gb + k0);
    __syncthreads();
    bf16x8 af[2], bfr[2];
    #pragma unroll
    for (int mi=0;mi<2;mi++)
      af[mi] = *(bf16x8*)(&As[(wm + mi*16 + l15)*LDT + quad*8]);
    #pragma unroll
    for (int nj=0;nj<2;nj++)
      bfr[nj] = *(bf16x8*)(&Bs[(wn + nj*16 + l15)*LDT + quad*8]);
    #pragma unroll
    for (int mi=0;mi<2;mi++)
      #pragma unroll
      for (int nj=0;nj<2;nj++)
        acc[mi][nj] = __builtin_amdgcn_mfma_f32_16x16x32_bf16(af[mi], bfr[nj], acc[mi][nj], 0,0,0);
    __syncthreads();
  }
  int rbase = quad*4;
  #pragma unroll
  for (int nj=0;nj<2;nj++){
    int gc = n0 + wn + nj*16 + l15;
    float bv = bias[gc];
    #pragma unroll
    for (int mi=0;mi<2;mi++){
      #pragma unroll
      for (int reg=0;reg<4;reg++){
        int gr = m0 + wm + mi*16 + rbase + reg;
        outv[(size_t)gr*Nt + gc] = acc[mi][nj][reg] + bv + res[(size_t)gr*Nt + gc];
      }
    }
  }
}

// ---------------- fused q/kv/sr 64x64 GEMM, reg staging, ONE launch ------------
__global__ __launch_bounds__(256) void gemm64f(const u16* __restrict__ A,
                                               const u16* __restrict__ W0,
                                               const u16* __restrict__ W1,
                                               const u16* __restrict__ W2,
                                               const float* __restrict__ b0,
                                               const float* __restrict__ b1,
                                               const float* __restrict__ b2,
                                               u16* __restrict__ o0,
                                               u16* __restrict__ o1,
                                               u16* __restrict__ o2){
  constexpr int LDT = 40;
  __shared__ u16 As[64*LDT];
  __shared__ u16 Bs[64*LDT];
  int tid = threadIdx.x, lane = tid & 63;
  int wave = tid >> 6;
  int m0 = blockIdx.x*64, y = blockIdx.y;
  const u16* Wp; const float* bp; u16* dst; int dld, dcol0; bool act = false;
  if (y < 4)      { Wp = W0 + (size_t)y*64*C_;      bp = b0 + y*64;      dst = o0; dld = 256; dcol0 = y*64; }
  else if (y < 12){ Wp = W1 + (size_t)(y-4)*64*C_;  bp = b1 + (y-4)*64;  dst = o1; dld = 512; dcol0 = (y-4)*64; }
  else            { Wp = W2 + (size_t)(y-12)*64*C_; bp = b2 + (y-12)*64; dst = o2; dld = 256; dcol0 = (y-12)*64; act = true; }
  int wm = (wave>>1)*32, wn = (wave&1)*32;
  f32x4 acc[2][2];
  #pragma unroll
  for (int i=0;i<2;i++)
    #pragma unroll
    for (int j=0;j<2;j++) acc[i][j] = (f32x4){0.f,0.f,0.f,0.f};

  const int l15 = lane & 15, quad = lane >> 4;
  int r  = tid >> 2;
  int c8 = (tid & 3) * 8;

  #pragma unroll 1
  for (int k0=0; k0<256; k0+=32){
    int gk = k0 + c8;
    *(u16x8*)(&As[r*LDT + c8]) = *(const u16x8*)(A  + (size_t)(m0+r)*C_ + gk);
    *(u16x8*)(&Bs[r*LDT + c8]) = *(const u16x8*)(Wp + (size_t)r*C_ + gk);
    __syncthreads();
    bf16x8 af[2], bfr[2];
    #pragma unroll
    for (int mi=0;mi<2;mi++)
      af[mi] = *(bf16x8*)(&As[(wm + mi*16 + l15)*LDT + quad*8]);
    #pragma unroll
    for (int nj=0;nj<2;nj++)
      bfr[nj] = *(bf16x8*)(&Bs[(wn + nj*16 + l15)*LDT + quad*8]);
    #pragma unroll
    for (int mi=0;mi<2;mi++)
      #pragma unroll
      for (int nj=0;nj<2;nj++)
        acc[mi][nj] = __builtin_amdgcn_mfma_f32_16x16x32_bf16(af[mi], bfr[nj], acc[mi][nj], 0,0,0);
    __syncthreads();
  }
  int rbase = quad*4;
  #pragma unroll
  for (int nj=0;nj<2;nj++){
    int cc = wn + nj*16 + l15;
    float bv = bp[cc];
    #pragma unroll
    for (int mi=0;mi<2;mi++){
      #pragma unroll
      for (int reg=0;reg<4;reg++){
        int gr = m0 + wm + mi*16 + rbase + reg;
        float v = acc[mi][nj][reg] + bv;
        if (act) v = gelu_f(v);
        dst[(size_t)gr*dld + dcol0 + cc] = f2bf(v);
      }
    }
  }
}

// ---------------- m97-structure GEMM, 128x128 tile, BK=32, gld_lds staging -----
template<int EPI>
__global__ __launch_bounds__(256) void gemm128t(const u16* __restrict__ A, int lda,
                                                const u16* __restrict__ W0,
                                                const float* __restrict__ b0,
                                                u16* __restrict__ o0,
                                                int M, int Nt, int K, int ldo){
  __shared__ u16 smem[8704];
  u16* As = smem;
  u16* Bs = smem + 4096;
  int tid = threadIdx.x, lane = tid & 63, wave = tid >> 6;
  int m0 = blockIdx.x*128, y = blockIdx.y;
  int wm = (wave>>1)*64, wn = (wave&1)*64;
  int l15 = lane & 15, quad = lane >> 4;

  const u16* Wp = W0 + (size_t)y*128*(size_t)lda;
  const float* bp = b0;
  u16* dstb = o0; int dld = ldo, dcol0 = y*128;

  f32x4 acc[4][4];
  #pragma unroll
  for (int i=0;i<4;i++)
    #pragma unroll
    for (int j=0;j<4;j++) acc[i][j] = (f32x4){0.f,0.f,0.f,0.f};

  const int Kt = (K + 31) & ~31;
  const u16* ga = A  + (size_t)(m0 + lane)*lda + wave*8;
  const u16* gb = Wp + (size_t)lane*lda + wave*8;
  u16* la = As + wave*1024;
  u16* lb = Bs + wave*1024;

  for (int k0=0; k0<Kt; k0+=32){
    gld_lds16(ga + k0,            la);
    gld_lds16(ga + 64*lda + k0,   la + 512);
    gld_lds16(gb + k0,            lb);
    gld_lds16(gb + 64*lda + k0,   lb + 512);
    __syncthreads();
    bf16x8 af[4], bfr[4];
    #pragma unroll
    for (int mi=0;mi<4;mi++)
      af[mi] = *(bf16x8*)(&As[quad*1024 + (wm + mi*16 + l15)*8]);
    #pragma unroll
    for (int nj=0;nj<4;nj++)
      bfr[nj] = *(bf16x8*)(&Bs[quad*1024 + (wn + nj*16 + l15)*8]);
    #pragma unroll
    for (int mi=0;mi<4;mi++)
      #pragma unroll
      for (int nj=0;nj<4;nj++)
        acc[mi][nj] = __builtin_amdgcn_mfma_f32_16x16x32_bf16(af[mi], bfr[nj], acc[mi][nj], 0,0,0);
    __syncthreads();
  }

  u16* Cs = smem;
  #pragma unroll
  for (int p=0;p<2;p++){
    if (wm == p*64){
      #pragma unroll
      for (int nj=0;nj<4;nj++){
        int cc = wn + nj*16 + l15;
        int gc = dcol0 + cc;
        float bv = (gc < Nt) ? bp[gc] : 0.f;
        #pragma unroll
        for (int mi=0;mi<4;mi++){
          #pragma unroll
          for (int reg=0;reg<4;reg++){
            int rr = mi*16 + quad*4 + reg;
            Cs[rr*136 + cc] = f2bf(acc[mi][nj][reg] + bv);
          }
        }
      }
    }
    __syncthreads();
    int r = tid >> 2, cb = (tid & 3)*32;
    int gr = m0 + p*64 + r;
    if (gr < M){
      u16* op = dstb + (size_t)gr*dld + dcol0;
      #pragma unroll
      for (int k=0;k<4;k++){
        int c0 = cb + k*8;
        if (dcol0 + c0 + 8 <= ldo)
          *(u16x8*)(op + c0) = *(u16x8*)&Cs[r*136 + c0];
      }
    }
    __syncthreads();
  }
}

// ---------------- merged (vectorized rows): qpost+knorm (4 rows/blk) | pool_ln ----
__global__ __launch_bounds__(256) void post1_kernel(u16* __restrict__ q,
                                                    const float* __restrict__ qe,
                                                    const float* __restrict__ temp,
                                                    const float* __restrict__ sls,
                                                    u16* __restrict__ qs_out,
                                                    u16* __restrict__ kv,
                                                    const u16* __restrict__ xsr,
                                                    const float* __restrict__ npw,
                                                    const float* __restrict__ npb,
                                                    u16* __restrict__ xpln){
  __shared__ float s1[4], s2[4];
  int bid = blockIdx.x, tid = threadIdx.x;
  if (bid < MROWS/4){
    int wv = tid>>6, l = tid&63;
    int row = bid*4 + wv;
    int c = l*4, h = l>>3;
    size_t idx = (size_t)row*C_ + c;
    ushort4 qv = *(const ushort4*)(q + idx);
    float v0=b2f(qv.x), v1=b2f(qv.y), v2=b2f(qv.z), v3=b2f(qv.w);
    float ss = rsum8(v0*v0+v1*v1+v2*v2+v3*v3);
    float inv = 1.0f / fmaxf(sqrtf(ss), 1e-12f);
    float qn0=v0*inv, qn1=v1*inv, qn2=v2*inv, qn3=v3*inv;
    ushort4 qo; qo.x=f2bf(qn0); qo.y=f2bf(qn1); qo.z=f2bf(qn2); qo.w=f2bf(qn3);
    *(ushort4*)(q + idx) = qo;
    float t  = temp[h];
    float sp = log1pf(expf(t));
    float scale = sp * sls[0];
    float4 qev = *(const float4*)(qe + c);
    ushort4 so;
    so.x = f2bf((qn0 + qev.x)*scale);
    so.y = f2bf((qn1 + qev.y)*scale);
    so.z = f2bf((qn2 + qev.z)*scale);
    so.w = f2bf((qn3 + qev.w)*scale);
    *(ushort4*)(qs_out + idx) = so;
    size_t kidx = (size_t)row*512 + c;
    ushort4 kvv = *(const ushort4*)(kv + kidx);
    float k0=b2f(kvv.x), k1=b2f(kvv.y), k2=b2f(kvv.z), k3=b2f(kvv.w);
    float ks = rsum8(k0*k0+k1*k1+k2*k2+k3*k3);
    float kinv = 1.0f / fmaxf(sqrtf(ks), 1e-12f);
    ushort4 ko; ko.x=f2bf(k0*kinv); ko.y=f2bf(k1*kinv); ko.z=f2bf(k2*kinv); ko.w=f2bf(k3*kinv);
    *(ushort4*)(kv + kidx) = ko;
  } else {
    int blk = bid - MROWS/4;          // 0..391
    int b = blk/PL_; int p = blk%PL_;
    int py = p/7, px = p%7;
    int o = tid;
    float s = 0.f;
    for (int iy=0;iy<8;iy++){
      const u16* rowp = xsr + ((size_t)(b*N_ + (py*8+iy)*WW + px*8))*C_ + o;
      #pragma unroll
      for (int ix=0;ix<8;ix++) s += b2f(rowp[(size_t)ix*C_]);
    }
    s *= (1.0f/64.0f);
    float su = rsum64(s), sq = rsum64(s*s);
    if ((o&63)==0){ s1[o>>6]=su; s2[o>>6]=sq; }
    __syncthreads();
    float ts=s1[0]+s1[1]+s1[2]+s1[3];
    float tq=s2[0]+s2[1]+s2[2]+s2[3];
    float m = ts*(1.0f/256.0f), var = tq*(1.0f/256.0f)-m*m;
    float inv = rsqrtf(var+1e-5f);
    xpln[(size_t)blk*C_+o] = f2bf((s-m)*inv*npw[o]+npb[o]);
  }
}

// ---------------- merged: kvp2 knorm (blocks 0..391) | cpb MLP (392..1415) -----
__global__ __launch_bounds__(256) void misc2_kernel(u16* __restrict__ kvp2,
                                                    const float* __restrict__ rct,
                                                    const float* __restrict__ w1,
                                                    const float* __restrict__ b1,
                                                    const float* __restrict__ w2,
                                                    const float* __restrict__ b2v,
                                                    float* __restrict__ cpb){
  __shared__ float r[512];
  int bid = blockIdx.x, tid = threadIdx.x;
  if (bid < B_*PL_){
    int row = bid;
    size_t idx = (size_t)row*512 + tid;
    float v = b2f(kvp2[idx]);
    float ss = rsum32(v*v);
    kvp2[idx] = f2bf(v / fmaxf(sqrtf(ss), 1e-12f));
  } else {
    int t = bid - B_*PL_;             // 0..1023
    float c0 = rct[t*2], c1 = rct[t*2+1];
    for (int j=tid;j<512;j+=256){
      float v = c0*w1[j*2] + c1*w1[j*2+1] + b1[j];
      r[j] = fmaxf(v, 0.f);
    }
    __syncthreads();
    int h = tid>>5, lane = tid&31;
    float s = 0.f;
    for (int j=lane;j<512;j+=32) s += r[j]*w2[h*512+j];
    s = rsum32(s);
    if (lane==0) cpb[t*8+h] = s + b2v[h];
  }
}

// ---------------- merged: qlt gemm (0..783) | attn_local (784..1567) | attn_pool ----
__global__ __launch_bounds__(256) void attn_all(const u16* __restrict__ qbuf,
                                                const u16* __restrict__ w72,
                                                const float* __restrict__ lb,
                                                float* __restrict__ qlt,
                                                const u16* __restrict__ qs,
                                                const u16* __restrict__ kv,
                                                const float* __restrict__ rpb,
                                                const u16* __restrict__ kvp2,
                                                const float* __restrict__ cpb,
                                                const int* __restrict__ ridx,
                                                float* __restrict__ attn){
  constexpr int LDT = 40;
  __shared__ u16 As[64*LDT];
  __shared__ u16 Bs[64*LDT];
  int bid = blockIdx.x, tid = threadIdx.x;
  int lane = tid & 63, wave = tid >> 6;
  int l15 = lane & 15, quad = lane >> 4;
  if (bid < 784){
    int m0 = (bid % 392)*64, n0 = (bid / 392)*64;
    int wm = (wave>>1)*32, wn = (wave&1)*32;
    f32x4 acc[2][2];
    #pragma unroll
    for (int i=0;i<2;i++)
      #pragma unroll
      for (int j=0;j<2;j++) acc[i][j] = (f32x4){0.f,0.f,0.f,0.f};
    int r  = tid >> 2;
    int c8 = (tid & 3) * 8;
    for (int k0=0; k0<256; k0+=32){
      int gk = k0 + c8;
      *(u16x8*)(&As[r*LDT + c8]) = *(const u16x8*)(qbuf + (size_t)(m0+r)*C_ + gk);
      u16x8 bv = (u16x8){0,0,0,0,0,0,0,0};
      if (n0 + r < 72)
        bv = *(const u16x8*)(w72 + (size_t)(n0+r)*C_ + gk);
      *(u16x8*)(&Bs[r*LDT + c8]) = bv;
      __syncthreads();
      bf16x8 af[2], bfr[2];
      #pragma unroll
      for (int mi=0;mi<2;mi++)
        af[mi] = *(bf16x8*)(&As[(wm + mi*16 + l15)*LDT + quad*8]);
      #pragma unroll
      for (int nj=0;nj<2;nj++)
        bfr[nj] = *(bf16x8*)(&Bs[(wn + nj*16 + l15)*LDT + quad*8]);
      #pragma unroll
      for (int mi=0;mi<2;mi++)
        #pragma unroll
        for (int nj=0;nj<2;nj++)
          acc[mi][nj] = __builtin_amdgcn_mfma_f32_16x16x32_bf16(af[mi], bfr[nj], acc[mi][nj], 0,0,0);
      __syncthreads();
    }
    int rbase = quad*4;
    #pragma unroll
    for (int nj=0;nj<2;nj++){
      int gc = n0 + wn + nj*16 + l15;
      if (gc >= 72) continue;
      float bv = lb[gc];
      #pragma unroll
      for (int mi=0;mi<2;mi++){
        #pragma unroll
        for (int reg=0;reg<4;reg++){
          int gr = m0 + wm + mi*16 + rbase + reg;
          qlt[(size_t)gr*72 + gc] = acc[mi][nj][reg] + bv;
        }
      }
    }
  } else if (bid < 1568){
    int t = tid;
    int row = (bid-784)*32 + (t>>3);
    int h = t & 7;
    int b = row / N_, n = row - b*N_;
    int y = n / WW, x = n - y*WW;
    const u16* qp = qs + (size_t)row*C_ + h*32;
    float q[32];
    #pragma unroll
    for (int j=0;j<4;j++){
      u16x8 v = *(const u16x8*)(qp + j*8);
      #pragma unroll
      for (int e=0;e<8;e++) q[j*8+e] = b2f(v[e]);
    }
    float* arow = attn + ((size_t)row*8 + h)*58;
    #pragma unroll
    for (int l=0;l<9;l++){
      int yy = y + l/3 - 1, xx = x + l%3 - 1;
      float s = 0.f;
      if (yy>=0 && yy<HH && xx>=0 && xx<WW){
        const u16* kp = kv + ((size_t)(b*N_ + yy*WW + xx))*512 + h*32;
        #pragma unroll
        for (int j=0;j<4;j++){
          u16x8 kw = *(const u16x8*)(kp + j*8);
          #pragma unroll
          for (int e=0;e<8;e++) s = fmaf(q[j*8+e], b2f(kw[e]), s);
        }
      }
      arow[l] = s + rpb[h*9+l];
    }
  } else {
    int t = bid - 1568;               // 0..3135
    int xblk = t % 49, bh = t / 49;
    int b = bh >> 3, h = bh & 7;
    int n0 = (xblk*4 + wave)*16;
    bf16x8 af = *(const bf16x8*)(qs + ((size_t)(b*N_ + n0 + l15)*C_ + h*32 + quad*8));
    f32x4 acc[4];
    #pragma unroll
    for (int nj=0;nj<4;nj++){
      int p = nj*16 + l15;
      bf16x8 bfr = (bf16x8){0,0,0,0,0,0,0,0};
      if (p < PL_)
        bfr = *(const bf16x8*)(kvp2 + ((size_t)(b*PL_ + p)*512 + h*32 + quad*8));
      f32x4 z = (f32x4){0.f,0.f,0.f,0.f};
      acc[nj] = __builtin_amdgcn_mfma_f32_16x16x32_bf16(af, bfr, z, 0,0,0);
    }
    #pragma unroll
    for (int nj=0;nj<4;nj++){
      int p = nj*16 + l15;
      if (p >= PL_) continue;
      #pragma unroll
      for (int reg=0;reg<4;reg++){
        int n = n0 + quad*4 + reg;
        float bias = cpb[ridx[(size_t)n*PL_ + p]*8 + h];
        attn[((size_t)(b*N_ + n)*8 + h)*58 + 9 + p] = acc[nj][reg] + bias;
      }
    }
  }
}

// ---------------- fused softmax + x_local + x_pool -> out (bf16), parallel softmax ----
__global__ __launch_bounds__(256) void xout_v4(const float* __restrict__ qlt,
                                               const float* __restrict__ attn,
                                               const u16* __restrict__ kv,
                                               const u16* __restrict__ kvp2,
                                               u16* __restrict__ out){
  __shared__ float coef[4][472];
  int t = threadIdx.x, w = t>>6, l = t&63;
  int row = blockIdx.x*4 + w;
  int b = row / N_, n = row - b*N_;
  int y = n / WW, x = n - y*WW;
  const float* arow = attn + (size_t)row*464;
  for (int i=l; i<464; i+=64) coef[w][i] = arow[i];
  __syncthreads();
  int h = l>>3, k = l&7;
  float* ch = &coef[w][h*58];
  float e[8];
  float mx = -1e30f;
  #pragma unroll
  for (int i=0;i<8;i++){
    int j = k + i*8;
    e[i] = (j<58) ? ch[j] : -1e30f;
    mx = fmaxf(mx, e[i]);
  }
  mx = fmaxf(mx, __shfl_xor(mx,1,64));
  mx = fmaxf(mx, __shfl_xor(mx,2,64));
  mx = fmaxf(mx, __shfl_xor(mx,4,64));
  float s = 0.f;
  #pragma unroll
  for (int i=0;i<8;i++){
    int j = k + i*8;
    if (j<58){ e[i] = expf(e[i]-mx); s += e[i]; }
  }
  s += __shfl_xor(s,1,64);
  s += __shfl_xor(s,2,64);
  s += __shfl_xor(s,4,64);
  float inv = 1.f/s;
  #pragma unroll
  for (int i=0;i<8;i++){
    int j = k + i*8;
    if (j<58){
      float v = e[i]*inv;
      if (j<9) v += qlt[(size_t)row*72 + h*9 + j];
      ch[j] = v;
    }
  }
  __syncthreads();
  int c = l*4;
  float a0=0.f, a1=0.f, a2=0.f, a3=0.f;
  #pragma unroll
  for (int lw=0; lw<9; lw++){
    int yy = y + lw/3 - 1, xx = x + lw%3 - 1;
    if (yy>=0 && yy<HH && xx>=0 && xx<WW){
      ushort4 vv = *(const ushort4*)(kv + ((size_t)(b*N_ + yy*WW + xx))*512 + 256 + c);
      float cf = ch[lw];
      a0 = fmaf(cf, b2f(vv.x), a0);
      a1 = fmaf(cf, b2f(vv.y), a1);
      a2 = fmaf(cf, b2f(vv.z), a2);
      a3 = fmaf(cf, b2f(vv.w), a3);
    }
  }
  const u16* pb = kvp2 + (size_t)b*PL_*512 + 256 + c;
  #pragma unroll 7
  for (int p=0;p<49;p++){
    ushort4 vv = *(const ushort4*)(pb + (size_t)p*512);
    float cf = ch[9+p];
    a0 = fmaf(cf, b2f(vv.x), a0);
    a1 = fmaf(cf, b2f(vv.y), a1);
    a2 = fmaf(cf, b2f(vv.z), a2);
    a3 = fmaf(cf, b2f(vv.w), a3);
  }
  ushort4 o; o.x=f2bf(a0); o.y=f2bf(a1); o.z=f2bf(a2); o.w=f2bf(a3);
  *(ushort4*)(out + (size_t)row*C_ + c) = o;
}

// ---------------- depthwise 3x3 + gelu gate, 8 ch/thread, XCD-confined ----------------
__global__ __launch_bounds__(256) void dwconv_v4(const u16* __restrict__ hsrc,
                                                 const float* __restrict__ dwwT,
                                                 const float* __restrict__ dwb,
                                                 u16* __restrict__ hg){
  int b = blockIdx.x;
  int idx = blockIdx.y*256 + threadIdx.x;
  if (idx >= N_*86) return;
  int n = idx/86, g = idx - n*86;
  int pix = b*N_ + n;
  int y = n / WW, x = n - y*WW;
  const u16* hb = hsrc + (size_t)b*N_*HBLD;
  if (g < 85){
    int f = g*8;
    float s[8];
    #pragma unroll
    for (int e=0;e<8;e++) s[e] = dwb[f+e];
    #pragma unroll
    for (int l=0;l<9;l++){
      int yy = y + l/3 - 1, xx = x + l%3 - 1;
      if (yy>=0 && yy<HH && xx>=0 && xx<WW){
        u16x8 hv = *(const u16x8*)(hb + (size_t)(yy*WW+xx)*HBLD + f);
        const float* wv = dwwT + (size_t)l*684 + f;
        #pragma unroll
        for (int e=0;e<8;e++) s[e] = fmaf(b2f(hv[e]), wv[e], s[e]);
      }
    }
    const u16* vp = hsrc + (size_t)pix*HBLD + HF_ + f;
    u16 ov[8];
    #pragma unroll
    for (int e=0;e<8;e++) ov[e] = f2bf(gelu_f(s[e]) * b2f(vp[e]));
    *(u16x8*)(hg + (size_t)pix*HGLD + f) = *(u16x8*)ov;
  } else {
    float r[2];
    #pragma unroll
    for (int c=0;c<2;c++){
      int ff = 680 + c;
      float s = dwb[ff];
      #pragma unroll
      for (int l=0;l<9;l++){
        int yy = y + l/3 - 1, xx = x + l%3 - 1;
        if (yy>=0 && yy<HH && xx>=0 && xx<WW)
          s += b2f(hb[(size_t)(yy*WW+xx)*HBLD + ff]) * dwwT[(size_t)l*684 + ff];
      }
      r[c] = gelu_f(s) * b2f(hsrc[(size_t)pix*HBLD + HF_ + ff]);
    }
    u16* hp = hg + (size_t)pix*HGLD;
    ushort4 o1; o1.x = f2bf(r[0]); o1.y = f2bf(r[1]); o1.z = 0; o1.w = 0;
    *(ushort4*)(hp + 680) = o1;
    ushort4 z4 = {0,0,0,0};
    *(ushort4*)(hp + 684) = z4;
    *(ushort4*)(hp + 688) = z4;
    *(ushort4*)(hp + 692) = z4;
    *(ushort4*)(hp + 696) = z4;
    *(ushort4*)(hp + 700) = z4;
  }
}

extern "C" void kernel_launch(void* const* d_in, const int* in_sizes, int n_in,
                              void* d_out, int out_size, void* d_ws, size_t ws_size,
                              hipStream_t stream) {
  const float* x    = (const float*)d_in[0];
  const float* rct  = (const float*)d_in[1];
  const float* sls  = (const float*)d_in[2];
  const float* n1w  = (const float*)d_in[3];
  const float* n1b  = (const float*)d_in[4];
  const float* q_w  = (const float*)d_in[5];
  const float* q_b  = (const float*)d_in[6];
  const float* kv_w = (const float*)d_in[7];
  const float* kv_b = (const float*)d_in[8];
  const float* temp = (const float*)d_in[9];
  const float* qe   = (const float*)d_in[10];
  const float* rpb  = (const float*)d_in[11];
  const float* lt   = (const float*)d_in[12];
  const float* lb   = (const float*)d_in[13];
  const float* sr_w = (const float*)d_in[14];
  const float* sr_b = (const float*)d_in[15];
  const float* npw  = (const float*)d_in[16];
  const float* npb  = (const float*)d_in[17];
  const float* c1w  = (const float*)d_in[18];
  const float* c1b  = (const float*)d_in[19];
  const float* c2w  = (const float*)d_in[20];
  const float* c2b  = (const float*)d_in[21];
  const float* pw   = (const float*)d_in[22];
  const float* pb   = (const float*)d_in[23];
  const float* n2w  = (const float*)d_in[24];
  const float* n2b  = (const float*)d_in[25];
  const float* f1w  = (const float*)d_in[26];
  const float* f1b  = (const float*)d_in[27];
  const float* dww  = (const float*)d_in[28];
  const float* dwb  = (const float*)d_in[29];
  const float* f2w  = (const float*)d_in[30];
  const float* f2bb = (const float*)d_in[31];
  const int*  ridx  = (const int*)d_in[32];
  float* outp = (float*)d_out;

  char* ws = (char*)d_ws;
  constexpr size_t SZ_BNC2 = (size_t)MROWS*C_*2;
  constexpr size_t SZ_KV2  = (size_t)MROWS*512*2;
  constexpr size_t SZ_ATTN = (size_t)MROWS*464*4;
  size_t o_xn   = 0;
  size_t o_qn   = o_xn   + SZ_BNC2;
  size_t o_qs   = o_qn   + SZ_BNC2;
  size_t o_kv   = o_qs   + SZ_BNC2;
  size_t o_attn = o_kv   + SZ_KV2;
  size_t o_xsr  = o_attn + SZ_ATTN;
  size_t o_xpln = o_xsr  + SZ_BNC2;
  size_t o_kvp2 = o_xpln + (size_t)B_*PL_*C_*2;
  size_t o_cpb  = o_kvp2 + (size_t)B_*PL_*512*2;
  size_t o_outb = o_cpb  + (size_t)1024*8*4;
  size_t o_x2   = o_outb + SZ_BNC2;
  size_t o_qlt  = o_x2   + (size_t)MROWS*C_*4;
  size_t o_wq   = o_qlt  + (size_t)MROWS*72*4;
  size_t o_wkv  = o_wq   + (size_t)65536*2;
  size_t o_wsr  = o_wkv  + (size_t)131072*2;
  size_t o_wp   = o_wsr  + (size_t)65536*2;
  size_t o_wf1  = o_wp   + (size_t)65536*2;
  size_t o_wf2  = o_wf1  + (size_t)360448*2;     // 1408 rows x 256 (row-padded)
  size_t o_w72  = o_wf2  + (size_t)256*F2LD*2;
  size_t o_dwwT = o_w72  + (size_t)72*256*2;
  size_t o_h    = o_kv;
  size_t o_hg   = 0;

  u16*   xn   = (u16*)(ws + o_xn);
  u16*   qbuf = (u16*)(ws + o_qn);
  u16*   qsc  = (u16*)(ws + o_qs);
  u16*   kv   = (u16*)(ws + o_kv);
  float* attn = (float*)(ws + o_attn);
  u16*   xsr  = (u16*)(ws + o_xsr);
  u16*   xpln = (u16*)(ws + o_xpln);
  u16*   kvp2 = (u16*)(ws + o_kvp2);
  float* cpb  = (float*)(ws + o_cpb);
  u16*   outb = (u16*)(ws + o_outb);
  float* x2   = (float*)(ws + o_x2);
  float* qlt  = (float*)(ws + o_qlt);
  u16*   wq   = (u16*)(ws + o_wq);
  u16*   wkv  = (u16*)(ws + o_wkv);
  u16*   wsr  = (u16*)(ws + o_wsr);
  u16*   wp   = (u16*)(ws + o_wp);
  u16*   wf1  = (u16*)(ws + o_wf1);
  u16*   wf2  = (u16*)(ws + o_wf2);
  u16*   w72  = (u16*)(ws + o_w72);
  float* dwwT = (float*)(ws + o_dwwT);
  u16*   hbuf = (u16*)(ws + o_h);
  u16*   hg   = (u16*)(ws + o_hg);

  // 0. all weight conversions, one launch
  cvt_all<<<dim3(64,8), 256, 0, stream>>>(q_w, kv_w, sr_w, pw, f1w, f2w, lt, dww,
                                          wq, wkv, wsr, wp, wf1, wf2, w72, dwwT);
  // 1. xn = LN(x) -> bf16 (vectorized, 4 rows/block)
  ln4_kernel<<<MROWS/4, 256, 0, stream>>>(x, n1w, n1b, xn);
  // 2-6. fused q / kv / sr projections, one launch, reg-staged 64-tile (max TLP)
  gemm64f<<<dim3(392,16), 256, 0, stream>>>(xn, wq, wkv, wsr, q_b, kv_b, sr_b,
                                            qbuf, kv, xsr);
  // 4+5+7. q_norm + q_scaled + k l2norm (4 rows/blk, vectorized) | pool+LN (merged)
  post1_kernel<<<MROWS/4 + B_*PL_, 256, 0, stream>>>(qbuf, qe, temp, sls, qsc, kv,
                                                     xsr, npw, npb, xpln);
  // 8. kvp2 = xpln @ kv_w^T + kv_b -> bf16 (guarded small GEMM)
  gemm64b<0,0,1><<<dim3(7,8), 256, 0, stream>>>(xpln, C_, wkv, C_, kv_b, nullptr, kvp2, B_*PL_, 512, 256);
  // 9+10. kvp2 knorm | CPB MLP (merged)
  misc2_kernel<<<B_*PL_ + 1024, 256, 0, stream>>>(kvp2, rct, c1w, c1b, c2w, c2b, cpb);
  // 10b+11+12. qlt gemm | local logits | pooled logits (merged)
  attn_all<<<784 + 784 + 3136, 256, 0, stream>>>(qbuf, w72, lb, qlt,
                                                 qsc, kv, rpb, kvp2, cpb, ridx, attn);
  // 13+14. fused softmax + x_local + x_pool -> outb bf16
  xout_v4<<<MROWS/4, 256, 0, stream>>>(qlt, attn, kv, kvp2, outb);
  // 15. x2 = x + outb @ proj_w^T + proj_b -> f32 (reg-staged, unguarded)
  gemm64r<<<dim3(392,4), 256, 0, stream>>>(outb, C_, wp, C_, pb, x, x2, 256, 256);
  // 16. xn2 = LN(x2) -> bf16 (vectorized, reuses xn)
  ln4_kernel<<<MROWS/4, 256, 0, stream>>>(x2, n2w, n2b, xn);
  // 17. h = xn2 @ fc1_w^T + fc1_b -> bf16 (ldo=HBLD, m97-structure 128-tile)
  gemm128t<0><<<dim3(196,11), 256, 0, stream>>>(xn, C_, wf1, f1b, hbuf, MROWS, 1364, 256, HBLD);
  // 18. hg = gelu(dwconv(h1)+dwb) * v -> bf16 (8 ch/thread, XCD-confined)
  dwconv_v4<<<dim3(8, (N_*86+255)/256), 256, 0, stream>>>(hbuf, dwwT, dwb, hg);
  // 19. out = x2 + hg @ fc2_w^T + fc2_b -> f32 (reg-staged, unguarded, K=704 padded)
  gemm64r<<<dim3(392,4), 256, 0, stream>>>(hg, HGLD, wf2, F2LD, f2bb, x2, outp, 256, 704);
}